// Round 22
// baseline (249.516 us; speedup 1.0000x reference)
//
#include <hip/hip_runtime.h>
#include <math.h>

#define NND 200000
#define NEV 100000
#define MD 100
#define TD 100
#define MSGD 172
#define NB 48             // nodes per gemm block (48 -> 46.7 KB LDS -> 3 blocks/CU)
#define NFRAG 25          // 400 output cols (200 rz-combined | 100 i_n | 100 h_n)
#define KS 15             // K = 480
#define BP_ELEMS (KS * NFRAG * 64 * 8)
#define GLS 50            // Gl node stride (word-stride 25, coprime 32 -> conflict-free)

typedef __attribute__((ext_vector_type(8))) short bf16x8;
typedef __attribute__((ext_vector_type(4))) float f32x4;

__device__ __forceinline__ float fast_sigmoid(float x) {
    return 1.0f / (1.0f + __expf(-x));
}
__device__ __forceinline__ float fast_tanh(float x) {
    return fmaf(2.0f, 1.0f / (1.0f + __expf(-2.0f * x)), -1.0f);
}

__device__ __forceinline__ unsigned short f2bf(float f) {
    union { float f; unsigned int u; } v; v.f = f;
    unsigned int r = (v.u + 0x7FFFu + ((v.u >> 16) & 1u)) >> 16;
    return (unsigned short)r;
}
__device__ __forceinline__ float bf2f(unsigned int h) {
    union { unsigned int u; float f; } v; v.u = h << 16;
    return v.f;
}
__device__ __forceinline__ unsigned int pk(float a, float b) {
    unsigned int r;
    asm("v_cvt_pk_bf16_f32 %0, %1, %2" : "=v"(r) : "v"(a), "v"(b));
    return r;  // lo = bf16(a), hi = bf16(b), RNE
}

// ---------------- K3a: 5-channel exclusive scan (cnt + 4 count-classes) ----------------
__global__ __launch_bounds__(256) void k_scan1(
    const int* __restrict__ cnt, int* __restrict__ off, int* __restrict__ tpos,
    int* __restrict__ psum, int* __restrict__ psumC)
{
    __shared__ int s[5][256];
    int t = threadIdx.x, b = blockIdx.x;
    int i0 = b * 1024 + t * 4;
    int v[4], cls[4];
#pragma unroll
    for (int j = 0; j < 4; ++j) {
        v[j] = (i0 + j < NND) ? cnt[i0 + j] : 0;
        cls[j] = (v[j] == 0) ? -1 : ((v[j] < 4 ? v[j] : 4) - 1);
    }
    int tsum = v[0] + v[1] + v[2] + v[3];
    int fs[4] = {0, 0, 0, 0};
#pragma unroll
    for (int j = 0; j < 4; ++j)
        if (cls[j] >= 0) fs[cls[j]]++;
    s[0][t] = tsum;
#pragma unroll
    for (int X = 0; X < 4; ++X) s[1 + X][t] = fs[X];
    __syncthreads();
    for (int o = 1; o < 256; o <<= 1) {
        int x[5];
#pragma unroll
        for (int ch = 0; ch < 5; ++ch) x[ch] = (t >= o) ? s[ch][t - o] : 0;
        __syncthreads();
#pragma unroll
        for (int ch = 0; ch < 5; ++ch) s[ch][t] += x[ch];
        __syncthreads();
    }
    int e0 = s[0][t] - tsum;
    int eC[4];
#pragma unroll
    for (int X = 0; X < 4; ++X) eC[X] = s[1 + X][t] - fs[X];
    int run = 0;
    int cseen[4] = {0, 0, 0, 0};
#pragma unroll
    for (int j = 0; j < 4; ++j) {
        int i = i0 + j;
        if (i < NND) {
            off[i] = e0 + run;
            if (cls[j] >= 0) tpos[i] = eC[cls[j]] + cseen[cls[j]];
        }
        run += v[j];
        if (cls[j] >= 0) cseen[cls[j]]++;
    }
    if (t == 255) {
        psum[b] = s[0][255];
#pragma unroll
        for (int X = 0; X < 4; ++X) psumC[X * 256 + b] = s[1 + X][255];
    }
}

// ---------------- K3b: scan block sums (5 ch); class bases + touched total ----------------
__global__ __launch_bounds__(256) void k_scan2(
    int* __restrict__ psum, int* __restrict__ psumC,
    int* __restrict__ clsBase, int* __restrict__ ntp, int nblk)
{
    __shared__ int s[5][256];
    int t = threadIdx.x;
    int v[5];
    v[0] = (t < nblk) ? psum[t] : 0;
#pragma unroll
    for (int X = 0; X < 4; ++X) v[1 + X] = (t < nblk) ? psumC[X * 256 + t] : 0;
#pragma unroll
    for (int ch = 0; ch < 5; ++ch) s[ch][t] = v[ch];
    __syncthreads();
    for (int o = 1; o < 256; o <<= 1) {
        int x[5];
#pragma unroll
        for (int ch = 0; ch < 5; ++ch) x[ch] = (t >= o) ? s[ch][t - o] : 0;
        __syncthreads();
#pragma unroll
        for (int ch = 0; ch < 5; ++ch) s[ch][t] += x[ch];
        __syncthreads();
    }
    if (t < nblk) {
        psum[t] = s[0][t] - v[0];
#pragma unroll
        for (int X = 0; X < 4; ++X) psumC[X * 256 + t] = s[1 + X][t] - v[1 + X];
    }
    if (t == 0) {
        int T0 = s[1][nblk - 1], T1 = s[2][nblk - 1];
        int T2 = s[3][nblk - 1], T3 = s[4][nblk - 1];
        clsBase[0] = 0;
        clsBase[1] = T0;
        clsBase[2] = T0 + T1;
        clsBase[3] = T0 + T1 + T2;
        ntp[0] = T0 + T1 + T2 + T3;
    }
}

// ---------------- K3c: add bases; finalize tpos; init cursor ----------------
__global__ __launch_bounds__(256) void k_scan3(
    const int* __restrict__ cnt, int* __restrict__ off, int* __restrict__ tpos,
    const int* __restrict__ psum, const int* __restrict__ psumC,
    const int* __restrict__ clsBase, int* __restrict__ cur)
{
    int t = threadIdx.x, b = blockIdx.x;
    int base = psum[b];
    int i0 = b * 1024 + t * 4;
#pragma unroll
    for (int j = 0; j < 4; ++j) {
        int i = i0 + j;
        if (i < NND) {
            int v = off[i] + base;
            off[i] = v;
            cur[i] = v;
            int c = cnt[i];
            if (c > 0) {
                int cls = (c < 4 ? c : 4) - 1;
                tpos[i] = clsBase[cls] + psumC[cls * 256 + b] + tpos[i];
            }
        }
    }
}

// ---------------- K_convert: weight-prep + raw->bf16 + event count ----------------
__global__ __launch_bounds__(256) void k_convert(
    const float* __restrict__ w_ih, const float* __restrict__ w_hh,
    const float* __restrict__ raw_msg,
    const int* __restrict__ src, const int* __restrict__ dst,
    unsigned short* __restrict__ Bp, uint4* __restrict__ rawbf,
    int* __restrict__ cnt)
{
    int idx = blockIdx.x * 256 + threadIdx.x;
    if (idx < BP_ELEMS) {
        int e = idx & 7;
        int lane = (idx >> 3) & 63;
        int t = idx >> 9;          // frag id = ks*25 + nf
        int nf = t % 25;
        int ks = t / 25;
        int col = nf * 16 + (lane & 15);
        int k = ks * 32 + ((lane >> 4) << 3) + e;
        float v = 0.0f;
        if (col < 200) {
            if (k < 472) v = w_ih[col * 472 + k];
            if (k < 100) v += w_hh[col * 100 + k];
        } else if (col < 300) {
            if (k < 472) v = w_ih[col * 472 + k];
        } else {
            if (k < 100) v = w_hh[(col - 100) * 100 + k];
        }
        Bp[idx] = f2bf(v);
        return;
    }
    int j = idx - BP_ELEMS;
    if (j < NEV * 22) {
        int e = j / 22, r = j - e * 22;
        const float4* rs = reinterpret_cast<const float4*>(raw_msg + (size_t)e * MSGD);
        float4 x = rs[2 * r];
        float4 y = (float4){0.f, 0.f, 0.f, 0.f};
        if (2 * r + 1 < 43) y = rs[2 * r + 1];
        uint4 o;
        o.x = pk(x.x, x.y); o.y = pk(x.z, x.w);
        o.z = pk(y.x, y.y); o.w = pk(y.z, y.w);
        rawbf[j] = o;
        return;
    }
    j -= NEV * 22;
    if (j < NEV) {
        atomicAdd(&cnt[src[j]], 1);
        atomicAdd(&cnt[dst[j]], 1);
    }
}

// ---------------- K_placecopy: membf + untouched-copy + tinfo + place-entries ----------------
__global__ __launch_bounds__(256) void k_placecopy(
    const float* __restrict__ memory, const int* __restrict__ cnt,
    const int* __restrict__ off, const int* __restrict__ tpos,
    const int* __restrict__ src, const int* __restrict__ dst,
    const int* __restrict__ tarr, const int* __restrict__ last_update,
    int* __restrict__ cur, float* __restrict__ out,
    uint4* __restrict__ membf, int4* __restrict__ tinfo, int4* __restrict__ entries)
{
    int idx = blockIdx.x * 256 + threadIdx.x;
    if (idx < NND * 13) {
        int node = idx / 13, u = idx - node * 13;
        int c = cnt[node];
        const float4* ms = reinterpret_cast<const float4*>(memory + (size_t)node * MD);
        uint4 o = (uint4){0u, 0u, 0u, 0u};
        if (u < 12) {
            float4 x = ms[2 * u], y = ms[2 * u + 1];
            o.x = pk(x.x, x.y); o.y = pk(x.z, x.w);
            o.z = pk(y.x, y.y); o.w = pk(y.z, y.w);
            if (c == 0) {
                float4* o4 = reinterpret_cast<float4*>(out) + (size_t)node * 25;
                o4[2 * u] = x;
                o4[2 * u + 1] = y;
            }
        } else {
            float4 x = ms[24];
            o.x = pk(x.x, x.y); o.y = pk(x.z, x.w);   // cols 100..103 stay zero
            if (c == 0) {
                reinterpret_cast<float4*>(out)[(size_t)node * 25 + 24] = x;
            }
        }
        membf[idx] = o;
        if (c > 0 && u == 0) {
            tinfo[tpos[node]] = make_int4(node, c, off[node], 0);
        }
        return;
    }
    int e = idx - NND * 13;
    if (e < NEV) {
        int s = src[e], d = dst[e], tt = tarr[e];
        int slot = atomicAdd(&cur[s], 1);
        entries[slot] = make_int4(d, e, __float_as_int((float)(tt - last_update[s])), s);
        slot = atomicAdd(&cur[d], 1);
        entries[slot] = make_int4(s, e, __float_as_int((float)(tt - last_update[d])), d);
    }
}

// ---------------- K_tenc: per-slot time-encoding table (bf16, row stride 50 u32) ----------------
__global__ __launch_bounds__(256) void k_tenc(
    const int4* __restrict__ entries, const float* __restrict__ time_w,
    const float* __restrict__ time_b, unsigned int* __restrict__ tencbf)
{
    int slot = blockIdx.x * 2 + (threadIdx.x >> 7);
    int k = threadIdx.x & 127;
    if (k >= 50) return;
    float trel = __int_as_float(entries[slot].z);
    float2 w = *reinterpret_cast<const float2*>(time_w + 2 * k);
    float2 b = *reinterpret_cast<const float2*>(time_b + 2 * k);
    tencbf[(size_t)slot * 50 + k] =
        pk(__cosf(fmaf(trel, w.x, b.x)), __cosf(fmaf(trel, w.y, b.y)));
}

// ---------------- K_gemm: 48-node tile, uniform-gather stage + bf16 MFMA GRU ----------------
// Block b handles touched slots [b*48, b*48+48). Wave handles 6 slots (2 batches of 3).
__global__ __launch_bounds__(512, 4) void tgn_gemm(
    const uint4* __restrict__ membf, const uint4* __restrict__ rawbf,
    const unsigned int* __restrict__ tencbf, const int4* __restrict__ entries,
    const unsigned short* __restrict__ Bp,
    const float* __restrict__ b_ih, const float* __restrict__ b_hh,
    const int* __restrict__ ntp, const int4* __restrict__ tinfo,
    float* __restrict__ out)
{
    __shared__ __align__(16) unsigned short lds[NB * 480];  // A tile; reused as Gl[400][GLS]
    __shared__ int node_s[NB], cnt_s[NB], off_s[NB];
    int tid = threadIdx.x;
    int n0 = blockIdx.x * NB;
    int nt = ntp[0];
    if (n0 >= nt) return;

    if (tid < NB) {
        int slot = n0 + tid;
        if (slot < nt) {
            int4 ti = tinfo[slot];
            node_s[tid] = ti.x; cnt_s[tid] = ti.y; off_s[tid] = ti.z;
        } else {
            node_s[tid] = -1; cnt_s[tid] = 0; off_s[tid] = 0;
        }
    }
    __syncthreads();

    int lane = tid & 63;
    int wv = tid >> 6;

    // ---- staging: lane-uniform dual 8B gathers; 2 batches of 3 slots ----
    {
        int u = lane;
        const char* membc = reinterpret_cast<const char*>(membf);
        const char* rawbc = reinterpret_cast<const char*>(rawbf);
        const char* tencbc = reinterpret_cast<const char*>(tencbf);
        // descriptor: sel 0=en.x 1=en.y 2=slot 3=off
        int selA = 3, selB = 3, strA = 0, strB = 0;
        const char* bA = membc;
        const char* bB = membc;
        if (u == 12) { selB = 0; strB = 208; bB = membc; }
        else if (u >= 13 && u <= 24) { selA = selB = 0; strA = strB = 208; bA = membc + 16 * u - 200; bB = bA + 8; }
        else if (u >= 25 && u <= 45) { selA = selB = 1; strA = strB = 352; bA = rawbc + 16 * u - 400; bB = bA + 8; }
        else if (u == 46) { selA = 1; strA = 352; bA = rawbc + 336; selB = 2; strB = 200; bB = tencbc; }
        else if (u >= 47 && u <= 58) { selA = selB = 2; strA = strB = 200; bA = tencbc + 16 * u - 744; bB = bA + 8; }
        bool enA = (selA != 3), enB = (selB != 3);

        auto gidx = [](int sel, int4 e, int slotId) {
            return (sel == 0) ? e.x : ((sel == 1) ? e.y : slotId);
        };

#pragma unroll
        for (int half = 0; half < 2; ++half) {
            int rb = wv * 6 + half * 3;
            int cc[3], oo[3];
#pragma unroll
            for (int r = 0; r < 3; ++r) { cc[r] = cnt_s[rb + r]; oo[r] = off_s[rb + r]; }
            int maxc = max(max(cc[0], cc[1]), cc[2]);
            int4 en[3];
#pragma unroll
            for (int r = 0; r < 3; ++r)
                en[r] = (cc[r] > 0) ? entries[oo[r]] : make_int4(0, 0, 0, 0);
            uint4 mreg[3];
#pragma unroll
            for (int r = 0; r < 3; ++r) {
                int nd = node_s[rb + r];
                mreg[r] = (u < 13 && nd >= 0) ? membf[(size_t)nd * 13 + u]
                                              : (uint4){0u, 0u, 0u, 0u};
            }
            uint2 gA[3], gB[3];
#pragma unroll
            for (int r = 0; r < 3; ++r) {
                gA[r] = (uint2){0u, 0u}; gB[r] = (uint2){0u, 0u};
                if (cc[r] > 0) {
                    if (enA) gA[r] = *reinterpret_cast<const uint2*>(
                        bA + (size_t)gidx(selA, en[r], oo[r]) * strA);
                    if (enB) gB[r] = *reinterpret_cast<const uint2*>(
                        bB + (size_t)gidx(selB, en[r], oo[r]) * strB);
                }
            }
            if (maxc <= 1) {
                // uniform passthrough (c<=1): mean of one message = the message
#pragma unroll
                for (int r = 0; r < 3; ++r) {
                    uint4 o;
                    if (u < 12)       o = mreg[r];
                    else if (u == 12) o = (uint4){mreg[r].x, mreg[r].y, gB[r].x, gB[r].y};
                    else              o = (uint4){gA[r].x, gA[r].y, gB[r].x, gB[r].y};
                    if (u < 60) {
                        int nl = rb + r;
                        int byte = (nl * 960 + 16 * u) ^ ((nl & 7) << 4);
                        *reinterpret_cast<uint4*>(reinterpret_cast<char*>(lds) + byte) = o;
                    }
                }
            } else {
                float ac[3][8];
#pragma unroll
                for (int r = 0; r < 3; ++r) {
                    ac[r][0] = bf2f(gA[r].x & 0xffffu); ac[r][1] = bf2f(gA[r].x >> 16);
                    ac[r][2] = bf2f(gA[r].y & 0xffffu); ac[r][3] = bf2f(gA[r].y >> 16);
                    ac[r][4] = bf2f(gB[r].x & 0xffffu); ac[r][5] = bf2f(gB[r].x >> 16);
                    ac[r][6] = bf2f(gB[r].y & 0xffffu); ac[r][7] = bf2f(gB[r].y >> 16);
                }
                for (int j = 1; j < maxc; ++j) {
                    int sl[3];
                    int4 e2[3];
#pragma unroll
                    for (int r = 0; r < 3; ++r) {
                        sl[r] = oo[r] + ((j < cc[r]) ? j : 0);
                        e2[r] = entries[sl[r]];
                    }
                    uint2 hA[3], hB[3];
#pragma unroll
                    for (int r = 0; r < 3; ++r) {
                        hA[r] = (uint2){0u, 0u}; hB[r] = (uint2){0u, 0u};
                        if (j < cc[r]) {
                            if (enA) hA[r] = *reinterpret_cast<const uint2*>(
                                bA + (size_t)gidx(selA, e2[r], sl[r]) * strA);
                            if (enB) hB[r] = *reinterpret_cast<const uint2*>(
                                bB + (size_t)gidx(selB, e2[r], sl[r]) * strB);
                        }
                    }
#pragma unroll
                    for (int r = 0; r < 3; ++r) {
                        if (j < cc[r]) {
                            ac[r][0] += bf2f(hA[r].x & 0xffffu); ac[r][1] += bf2f(hA[r].x >> 16);
                            ac[r][2] += bf2f(hA[r].y & 0xffffu); ac[r][3] += bf2f(hA[r].y >> 16);
                            ac[r][4] += bf2f(hB[r].x & 0xffffu); ac[r][5] += bf2f(hB[r].x >> 16);
                            ac[r][6] += bf2f(hB[r].y & 0xffffu); ac[r][7] += bf2f(hB[r].y >> 16);
                        }
                    }
                }
#pragma unroll
                for (int r = 0; r < 3; ++r) {
                    float ci = 1.0f / fmaxf((float)cc[r], 1.0f);
                    uint4 o;
                    if (u < 12) {
                        o = mreg[r];
                    } else {
                        o.x = (u == 12) ? mreg[r].x : pk(ac[r][0] * ci, ac[r][1] * ci);
                        o.y = (u == 12) ? mreg[r].y : pk(ac[r][2] * ci, ac[r][3] * ci);
                        o.z = pk(ac[r][4] * ci, ac[r][5] * ci);
                        o.w = pk(ac[r][6] * ci, ac[r][7] * ci);
                    }
                    if (u < 60) {
                        int nl = rb + r;
                        int byte = (nl * 960 + 16 * u) ^ ((nl & 7) << 4);
                        *reinterpret_cast<uint4*>(reinterpret_cast<char*>(lds) + byte) = o;
                    }
                }
            }
        }
    }
    __syncthreads();

    // ---- MFMA phase: 3 m-frags x (3-4) n-frags, fully unrolled K loop ----
    int l15 = lane & 15;
    int kg8 = (lane >> 4) << 3;
    int f0 = (wv == 0) ? 0 : (4 + 3 * (wv - 1));
    int cw = (wv == 0) ? 4 : 3;

    f32x4 acc[3][4];
#pragma unroll
    for (int g = 0; g < 3; ++g)
#pragma unroll
        for (int i = 0; i < 4; ++i) acc[g][i] = (f32x4){0.f, 0.f, 0.f, 0.f};

    const bf16x8* BpB = reinterpret_cast<const bf16x8*>(Bp);
    const char* ldsc = reinterpret_cast<const char*>(lds);

#pragma unroll
    for (int ks = 0; ks < KS; ++ks) {
        int k0 = ks * 32 + kg8;
        const bf16x8* bp = BpB + ((size_t)(ks * NFRAG + f0)) * 64 + lane;
        bf16x8 b[4];
#pragma unroll
        for (int i = 0; i < 4; ++i)
            if (i < cw) b[i] = bp[i * 64];
#pragma unroll
        for (int g = 0; g < 3; ++g) {
            int r = g * 16 + l15;
            int ab = (r * 960 + 2 * k0) ^ ((r & 7) << 4);
            bf16x8 a = *reinterpret_cast<const bf16x8*>(ldsc + ab);
#pragma unroll
            for (int i = 0; i < 4; ++i)
                if (i < cw)
                    acc[g][i] = __builtin_amdgcn_mfma_f32_16x16x32_bf16(a, b[i], acc[g][i], 0, 0, 0);
        }
    }

    // ---- epilogue mv prefetch (bf16 membf row of the slot's node) ----
    float mv[10];
    {
        const char* membc = reinterpret_cast<const char*>(membf);
#pragma unroll
        for (int t = 0; t < 10; ++t) {
            int idx = tid + t * 512;
            mv[t] = 0.f;
            if (idx < NB * MD) {
                int n = idx / MD, j = idx - n * MD;
                int nd = node_s[n];
                if (nd >= 0) {
                    unsigned short h = *reinterpret_cast<const unsigned short*>(
                        membc + (size_t)nd * 208 + 2 * j);
                    mv[t] = bf2f((unsigned int)h);
                }
            }
        }
    }

    __syncthreads();  // reuse LDS as Gl[400][GLS] bf16

    unsigned short* Gl = lds;
    int kq = (lane >> 4) << 2;
#pragma unroll
    for (int i = 0; i < 4; ++i) {
        if (i < cw) {
            int col = (f0 + i) * 16 + l15;
            float bias = (col < 200) ? (b_ih[col] + b_hh[col])
                       : (col < 300) ? b_ih[col] : b_hh[col - 100];
#pragma unroll
            for (int g = 0; g < 3; ++g) {
                int node = g * 16 + kq;
#pragma unroll
                for (int rp = 0; rp < 2; ++rp) {
                    *reinterpret_cast<unsigned int*>(&Gl[col * GLS + node + 2 * rp]) =
                        pk(acc[g][i][2 * rp] + bias, acc[g][i][2 * rp + 1] + bias);
                }
            }
        }
    }
    __syncthreads();

#pragma unroll
    for (int t = 0; t < 10; ++t) {
        int idx = tid + t * 512;
        if (idx < NB * MD) {
            int n = idx / MD, j = idx - n * MD;
            int nd = node_s[n];
            if (nd >= 0) {
                float rp = bf2f((unsigned int)Gl[j * GLS + n]);
                float zp = bf2f((unsigned int)Gl[(100 + j) * GLS + n]);
                float inp = bf2f((unsigned int)Gl[(200 + j) * GLS + n]);
                float hnp = bf2f((unsigned int)Gl[(300 + j) * GLS + n]);
                float r = fast_sigmoid(rp);
                float z = fast_sigmoid(zp);
                float nn = fast_tanh(fmaf(r, hnp, inp));
                float h = (1.0f - z) * nn + z * mv[t];
                out[(size_t)nd * MD + j] = h;
            }
        }
    }
}

extern "C" void kernel_launch(void* const* d_in, const int* in_sizes, int n_in,
                              void* d_out, int out_size, void* d_ws, size_t ws_size,
                              hipStream_t stream)
{
    const float* memory      = (const float*)d_in[0];
    const float* raw_msg     = (const float*)d_in[1];
    const float* time_w      = (const float*)d_in[2];
    const float* time_b      = (const float*)d_in[3];
    const float* w_ih        = (const float*)d_in[4];
    const float* w_hh        = (const float*)d_in[5];
    const float* b_ih        = (const float*)d_in[6];
    const float* b_hh        = (const float*)d_in[7];
    const int*   last_update = (const int*)d_in[8];
    const int*   src         = (const int*)d_in[9];
    const int*   dst         = (const int*)d_in[10];
    const int*   tarr        = (const int*)d_in[11];
    float* out = (float*)d_out;

    // ws: cnt[N] off[N] cur[N] tpos[N] psum[256] psumC[1024] clsBase[4] ntp[4]
    //     | entries int4[2E] | tinfo int4[N] | tencbf u32[2E*50]
    //     | membf uint4[N*13] | rawbf uint4[E*22] | Bp
    int* cnt     = (int*)d_ws;
    int* off     = cnt + NND;
    int* cur     = off + NND;
    int* tpos    = cur + NND;
    int* psum    = tpos + NND;
    int* psumC   = psum + 256;
    int* clsBase = psumC + 1024;
    int* ntp     = clsBase + 4;
    int4* entries = (int4*)(ntp + 4);
    int4* tinfo = entries + 2 * NEV;
    unsigned int* tencbf = (unsigned int*)(tinfo + NND);
    uint4* membf = (uint4*)(tencbf + (size_t)2 * NEV * 50);
    uint4* rawbf = membf + (size_t)NND * 13;
    unsigned short* Bp = (unsigned short*)(rawbf + (size_t)NEV * 22);
    size_t need = (size_t)((char*)(Bp + BP_ELEMS) - (char*)d_ws);
    if (ws_size < need) return;

    const int NBLK = (NND + 1023) / 1024;  // 196
    const int NTILE = (NND + NB - 1) / NB; // 4167
    const int CVT_TOTAL = BP_ELEMS + NEV * 22 + NEV;
    const int PC_TOTAL = NND * 13 + NEV;

    hipMemsetAsync(cnt, 0, NND * sizeof(int), stream);
    k_convert<<<(CVT_TOTAL + 255) / 256, 256, 0, stream>>>(w_ih, w_hh, raw_msg,
                                                           src, dst, Bp, rawbf, cnt);
    k_scan1<<<NBLK, 256, 0, stream>>>(cnt, off, tpos, psum, psumC);
    k_scan2<<<1, 256, 0, stream>>>(psum, psumC, clsBase, ntp, NBLK);
    k_scan3<<<NBLK, 256, 0, stream>>>(cnt, off, tpos, psum, psumC, clsBase, cur);
    k_placecopy<<<(PC_TOTAL + 255) / 256, 256, 0, stream>>>(memory, cnt, off, tpos,
                                                            src, dst, tarr, last_update,
                                                            cur, out, membf, tinfo, entries);
    k_tenc<<<NEV, 256, 0, stream>>>(entries, time_w, time_b, tencbf);
    tgn_gemm<<<NTILE, 512, 0, stream>>>(membf, rawbf, tencbf, entries,
                                        Bp, b_ih, b_hh, ntp, tinfo, out);
}

// Round 23
// 243.051 us; speedup vs baseline: 1.0266x; 1.0266x over previous
//
#include <hip/hip_runtime.h>
#include <math.h>

#define NND 200000
#define NEV 100000
#define MD 100
#define TD 100
#define MSGD 172
#define NB 64
#define NFRAG 25          // 400 output cols (200 rz-combined | 100 i_n | 100 h_n)
#define KS 15             // K = 480
#define BP_ELEMS (KS * NFRAG * 64 * 8)
#define GLS 74            // Gl node stride (word-stride 37, coprime 32 -> conflict-free)

typedef __attribute__((ext_vector_type(8))) short bf16x8;
typedef __attribute__((ext_vector_type(4))) float f32x4;

__device__ __forceinline__ float fast_sigmoid(float x) {
    return 1.0f / (1.0f + __expf(-x));
}
__device__ __forceinline__ float fast_tanh(float x) {
    return fmaf(2.0f, 1.0f / (1.0f + __expf(-2.0f * x)), -1.0f);
}

__device__ __forceinline__ unsigned short f2bf(float f) {
    union { float f; unsigned int u; } v; v.f = f;
    unsigned int r = (v.u + 0x7FFFu + ((v.u >> 16) & 1u)) >> 16;
    return (unsigned short)r;
}
__device__ __forceinline__ float bf2f(unsigned int h) {
    union { unsigned int u; float f; } v; v.u = h << 16;
    return v.f;
}
__device__ __forceinline__ unsigned int pk(float a, float b) {
    unsigned int r;
    asm("v_cvt_pk_bf16_f32 %0, %1, %2" : "=v"(r) : "v"(a), "v"(b));
    return r;  // lo = bf16(a), hi = bf16(b), RNE
}

// ---------------- K3a: 5-channel exclusive scan (cnt + 4 count-classes) ----------------
__global__ __launch_bounds__(256) void k_scan1(
    const int* __restrict__ cnt, int* __restrict__ off, int* __restrict__ tpos,
    int* __restrict__ psum, int* __restrict__ psumC)
{
    __shared__ int s[5][256];
    int t = threadIdx.x, b = blockIdx.x;
    int i0 = b * 1024 + t * 4;
    int v[4], cls[4];
#pragma unroll
    for (int j = 0; j < 4; ++j) {
        v[j] = (i0 + j < NND) ? cnt[i0 + j] : 0;
        cls[j] = (v[j] == 0) ? -1 : ((v[j] < 4 ? v[j] : 4) - 1);
    }
    int tsum = v[0] + v[1] + v[2] + v[3];
    int fs[4] = {0, 0, 0, 0};
#pragma unroll
    for (int j = 0; j < 4; ++j)
        if (cls[j] >= 0) fs[cls[j]]++;
    s[0][t] = tsum;
#pragma unroll
    for (int X = 0; X < 4; ++X) s[1 + X][t] = fs[X];
    __syncthreads();
    for (int o = 1; o < 256; o <<= 1) {
        int x[5];
#pragma unroll
        for (int ch = 0; ch < 5; ++ch) x[ch] = (t >= o) ? s[ch][t - o] : 0;
        __syncthreads();
#pragma unroll
        for (int ch = 0; ch < 5; ++ch) s[ch][t] += x[ch];
        __syncthreads();
    }
    int e0 = s[0][t] - tsum;
    int eC[4];
#pragma unroll
    for (int X = 0; X < 4; ++X) eC[X] = s[1 + X][t] - fs[X];
    int run = 0;
    int cseen[4] = {0, 0, 0, 0};
#pragma unroll
    for (int j = 0; j < 4; ++j) {
        int i = i0 + j;
        if (i < NND) {
            off[i] = e0 + run;
            if (cls[j] >= 0) tpos[i] = eC[cls[j]] + cseen[cls[j]];
        }
        run += v[j];
        if (cls[j] >= 0) cseen[cls[j]]++;
    }
    if (t == 255) {
        psum[b] = s[0][255];
#pragma unroll
        for (int X = 0; X < 4; ++X) psumC[X * 256 + b] = s[1 + X][255];
    }
}

// ---------------- K3b: scan block sums (5 ch); class bases + touched total ----------------
__global__ __launch_bounds__(256) void k_scan2(
    int* __restrict__ psum, int* __restrict__ psumC,
    int* __restrict__ clsBase, int* __restrict__ ntp, int nblk)
{
    __shared__ int s[5][256];
    int t = threadIdx.x;
    int v[5];
    v[0] = (t < nblk) ? psum[t] : 0;
#pragma unroll
    for (int X = 0; X < 4; ++X) v[1 + X] = (t < nblk) ? psumC[X * 256 + t] : 0;
#pragma unroll
    for (int ch = 0; ch < 5; ++ch) s[ch][t] = v[ch];
    __syncthreads();
    for (int o = 1; o < 256; o <<= 1) {
        int x[5];
#pragma unroll
        for (int ch = 0; ch < 5; ++ch) x[ch] = (t >= o) ? s[ch][t - o] : 0;
        __syncthreads();
#pragma unroll
        for (int ch = 0; ch < 5; ++ch) s[ch][t] += x[ch];
        __syncthreads();
    }
    if (t < nblk) {
        psum[t] = s[0][t] - v[0];
#pragma unroll
        for (int X = 0; X < 4; ++X) psumC[X * 256 + t] = s[1 + X][t] - v[1 + X];
    }
    if (t == 0) {
        int T0 = s[1][nblk - 1], T1 = s[2][nblk - 1];
        int T2 = s[3][nblk - 1], T3 = s[4][nblk - 1];
        clsBase[0] = 0;
        clsBase[1] = T0;
        clsBase[2] = T0 + T1;
        clsBase[3] = T0 + T1 + T2;
        ntp[0] = T0 + T1 + T2 + T3;
    }
}

// ---------------- K3c: add bases; finalize tpos; init cursor ----------------
__global__ __launch_bounds__(256) void k_scan3(
    const int* __restrict__ cnt, int* __restrict__ off, int* __restrict__ tpos,
    const int* __restrict__ psum, const int* __restrict__ psumC,
    const int* __restrict__ clsBase, int* __restrict__ cur)
{
    int t = threadIdx.x, b = blockIdx.x;
    int base = psum[b];
    int i0 = b * 1024 + t * 4;
#pragma unroll
    for (int j = 0; j < 4; ++j) {
        int i = i0 + j;
        if (i < NND) {
            int v = off[i] + base;
            off[i] = v;
            cur[i] = v;
            int c = cnt[i];
            if (c > 0) {
                int cls = (c < 4 ? c : 4) - 1;
                tpos[i] = clsBase[cls] + psumC[cls * 256 + b] + tpos[i];
            }
        }
    }
}

// ---------------- K_convert: weight-prep + raw->bf16 + event count ----------------
// ranges: [0,BP_ELEMS)=Bp | [+NEV*22)=rawbf | [+NEV)=count
__global__ __launch_bounds__(256) void k_convert(
    const float* __restrict__ w_ih, const float* __restrict__ w_hh,
    const float* __restrict__ raw_msg,
    const int* __restrict__ src, const int* __restrict__ dst,
    unsigned short* __restrict__ Bp, uint4* __restrict__ rawbf,
    int* __restrict__ cnt)
{
    int idx = blockIdx.x * 256 + threadIdx.x;
    if (idx < BP_ELEMS) {
        int e = idx & 7;
        int lane = (idx >> 3) & 63;
        int t = idx >> 9;          // frag id = ks*25 + nf
        int nf = t % 25;
        int ks = t / 25;
        int col = nf * 16 + (lane & 15);
        int k = ks * 32 + ((lane >> 4) << 3) + e;
        float v = 0.0f;
        if (col < 200) {
            if (k < 472) v = w_ih[col * 472 + k];
            if (k < 100) v += w_hh[col * 100 + k];
        } else if (col < 300) {
            if (k < 472) v = w_ih[col * 472 + k];
        } else {
            if (k < 100) v = w_hh[(col - 100) * 100 + k];
        }
        Bp[idx] = f2bf(v);
        return;
    }
    int j = idx - BP_ELEMS;
    if (j < NEV * 22) {
        int e = j / 22, r = j - e * 22;
        const float4* rs = reinterpret_cast<const float4*>(raw_msg + (size_t)e * MSGD);
        float4 x = rs[2 * r];
        float4 y = (float4){0.f, 0.f, 0.f, 0.f};
        if (2 * r + 1 < 43) y = rs[2 * r + 1];
        uint4 o;
        o.x = pk(x.x, x.y); o.y = pk(x.z, x.w);
        o.z = pk(y.x, y.y); o.w = pk(y.z, y.w);
        rawbf[j] = o;
        return;
    }
    j -= NEV * 22;
    if (j < NEV) {
        atomicAdd(&cnt[src[j]], 1);
        atomicAdd(&cnt[dst[j]], 1);
    }
}

// ---------------- K_placecopy: membf + untouched-copy + tinfo + place-entries ----------------
// range A [0, NND*13): unit u of node -> membf write; c==0 also copies out; u==0 touched -> tinfo.
// range B [NND*13, +NEV): place entries.
__global__ __launch_bounds__(256) void k_placecopy(
    const float* __restrict__ memory, const int* __restrict__ cnt,
    const int* __restrict__ off, const int* __restrict__ tpos,
    const int* __restrict__ src, const int* __restrict__ dst,
    const int* __restrict__ tarr, const int* __restrict__ last_update,
    int* __restrict__ cur, float* __restrict__ out,
    uint4* __restrict__ membf, int4* __restrict__ tinfo, int4* __restrict__ entries)
{
    int idx = blockIdx.x * 256 + threadIdx.x;
    if (idx < NND * 13) {
        int node = idx / 13, u = idx - node * 13;
        int c = cnt[node];
        const float4* ms = reinterpret_cast<const float4*>(memory + (size_t)node * MD);
        uint4 o = (uint4){0u, 0u, 0u, 0u};
        if (u < 12) {
            float4 x = ms[2 * u], y = ms[2 * u + 1];
            o.x = pk(x.x, x.y); o.y = pk(x.z, x.w);
            o.z = pk(y.x, y.y); o.w = pk(y.z, y.w);
            if (c == 0) {
                float4* o4 = reinterpret_cast<float4*>(out) + (size_t)node * 25;
                o4[2 * u] = x;
                o4[2 * u + 1] = y;
            }
        } else {
            float4 x = ms[24];
            o.x = pk(x.x, x.y); o.y = pk(x.z, x.w);   // cols 100..103 stay zero
            if (c == 0) {
                reinterpret_cast<float4*>(out)[(size_t)node * 25 + 24] = x;
            }
        }
        membf[idx] = o;
        if (c > 0 && u == 0) {
            tinfo[tpos[node]] = make_int4(node, c, off[node], 0);
        }
        return;
    }
    int e = idx - NND * 13;
    if (e < NEV) {
        int s = src[e], d = dst[e], tt = tarr[e];
        int slot = atomicAdd(&cur[s], 1);
        entries[slot] = make_int4(d, e, __float_as_int((float)(tt - last_update[s])), s);
        slot = atomicAdd(&cur[d], 1);
        entries[slot] = make_int4(s, e, __float_as_int((float)(tt - last_update[d])), d);
    }
}

// ---------------- K_tenc: per-slot time-encoding table (bf16, row stride 50 u32) ----------------
__global__ __launch_bounds__(256) void k_tenc(
    const int4* __restrict__ entries, const float* __restrict__ time_w,
    const float* __restrict__ time_b, unsigned int* __restrict__ tencbf)
{
    int slot = blockIdx.x * 2 + (threadIdx.x >> 7);
    int k = threadIdx.x & 127;
    if (k >= 50) return;
    float trel = __int_as_float(entries[slot].z);
    float2 w = *reinterpret_cast<const float2*>(time_w + 2 * k);
    float2 b = *reinterpret_cast<const float2*>(time_b + 2 * k);
    tencbf[(size_t)slot * 50 + k] =
        pk(__cosf(fmaf(trel, w.x, b.x)), __cosf(fmaf(trel, w.y, b.y)));
}

// ---------------- K_gemm: uniform-gather stage + bf16 MFMA GRU ----------------
__global__ __launch_bounds__(512, 4) void tgn_gemm(
    const uint4* __restrict__ membf, const uint4* __restrict__ rawbf,
    const unsigned int* __restrict__ tencbf, const int4* __restrict__ entries,
    const unsigned short* __restrict__ Bp,
    const float* __restrict__ b_ih, const float* __restrict__ b_hh,
    const int* __restrict__ ntp, const int4* __restrict__ tinfo,
    float* __restrict__ out)
{
    __shared__ __align__(16) unsigned short lds[64 * 480];  // A tile; reused as Gl[400][GLS]
    __shared__ int node_s[NB], cnt_s[NB], off_s[NB];
    int tid = threadIdx.x;
    int n0 = blockIdx.x * NB;
    int nt = ntp[0];
    if (n0 >= nt) return;

    if (tid < NB) {
        int slot = n0 + tid;
        if (slot < nt) {
            int4 ti = tinfo[slot];
            node_s[tid] = ti.x; cnt_s[tid] = ti.y; off_s[tid] = ti.z;
        } else {
            node_s[tid] = -1; cnt_s[tid] = 0; off_s[tid] = 0;
        }
    }
    __syncthreads();

    int lane = tid & 63;
    int wv = tid >> 6;

    // ---- staging: lane-uniform dual 8B gathers ----
    {
        int u = lane;
        const char* membc = reinterpret_cast<const char*>(membf);
        const char* rawbc = reinterpret_cast<const char*>(rawbf);
        const char* tencbc = reinterpret_cast<const char*>(tencbf);
        // descriptor: sel 0=en.x 1=en.y 2=slot 3=off
        int selA = 3, selB = 3, strA = 0, strB = 0;
        const char* bA = membc;
        const char* bB = membc;
        if (u == 12) { selB = 0; strB = 208; bB = membc; }
        else if (u >= 13 && u <= 24) { selA = selB = 0; strA = strB = 208; bA = membc + 16 * u - 200; bB = bA + 8; }
        else if (u >= 25 && u <= 45) { selA = selB = 1; strA = strB = 352; bA = rawbc + 16 * u - 400; bB = bA + 8; }
        else if (u == 46) { selA = 1; strA = 352; bA = rawbc + 336; selB = 2; strB = 200; bB = tencbc; }
        else if (u >= 47 && u <= 58) { selA = selB = 2; strA = strB = 200; bA = tencbc + 16 * u - 744; bB = bA + 8; }
        bool enA = (selA != 3), enB = (selB != 3);

        auto gidx = [](int sel, int4 e, int slotId) {
            return (sel == 0) ? e.x : ((sel == 1) ? e.y : slotId);
        };

#pragma unroll
        for (int half = 0; half < 2; ++half) {
            int rb = wv * 8 + half * 4;
            int cc[4], oo[4];
#pragma unroll
            for (int r = 0; r < 4; ++r) { cc[r] = cnt_s[rb + r]; oo[r] = off_s[rb + r]; }
            int maxc = max(max(cc[0], cc[1]), max(cc[2], cc[3]));
            int4 en[4];
#pragma unroll
            for (int r = 0; r < 4; ++r)
                en[r] = (cc[r] > 0) ? entries[oo[r]] : make_int4(0, 0, 0, 0);
            uint4 mreg[4];
#pragma unroll
            for (int r = 0; r < 4; ++r) {
                int nd = node_s[rb + r];
                mreg[r] = (u < 13 && nd >= 0) ? membf[(size_t)nd * 13 + u]
                                              : (uint4){0u, 0u, 0u, 0u};
            }
            uint2 gA[4], gB[4];
#pragma unroll
            for (int r = 0; r < 4; ++r) {
                gA[r] = (uint2){0u, 0u}; gB[r] = (uint2){0u, 0u};
                if (cc[r] > 0) {
                    if (enA) gA[r] = *reinterpret_cast<const uint2*>(
                        bA + (size_t)gidx(selA, en[r], oo[r]) * strA);
                    if (enB) gB[r] = *reinterpret_cast<const uint2*>(
                        bB + (size_t)gidx(selB, en[r], oo[r]) * strB);
                }
            }
            if (maxc <= 1) {
                // uniform passthrough (c<=1): mean of one message = the message
#pragma unroll
                for (int r = 0; r < 4; ++r) {
                    uint4 o;
                    if (u < 12)       o = mreg[r];
                    else if (u == 12) o = (uint4){mreg[r].x, mreg[r].y, gB[r].x, gB[r].y};
                    else              o = (uint4){gA[r].x, gA[r].y, gB[r].x, gB[r].y};
                    if (u < 60) {
                        int nl = rb + r;
                        int byte = (nl * 960 + 16 * u) ^ ((nl & 7) << 4);
                        *reinterpret_cast<uint4*>(reinterpret_cast<char*>(lds) + byte) = o;
                    }
                }
            } else {
                float ac[4][8];
#pragma unroll
                for (int r = 0; r < 4; ++r) {
                    ac[r][0] = bf2f(gA[r].x & 0xffffu); ac[r][1] = bf2f(gA[r].x >> 16);
                    ac[r][2] = bf2f(gA[r].y & 0xffffu); ac[r][3] = bf2f(gA[r].y >> 16);
                    ac[r][4] = bf2f(gB[r].x & 0xffffu); ac[r][5] = bf2f(gB[r].x >> 16);
                    ac[r][6] = bf2f(gB[r].y & 0xffffu); ac[r][7] = bf2f(gB[r].y >> 16);
                }
                for (int j = 1; j < maxc; ++j) {
                    int sl[4];
                    int4 e2[4];
#pragma unroll
                    for (int r = 0; r < 4; ++r) {
                        sl[r] = oo[r] + ((j < cc[r]) ? j : 0);
                        e2[r] = entries[sl[r]];
                    }
                    uint2 hA[4], hB[4];
#pragma unroll
                    for (int r = 0; r < 4; ++r) {
                        hA[r] = (uint2){0u, 0u}; hB[r] = (uint2){0u, 0u};
                        if (j < cc[r]) {
                            if (enA) hA[r] = *reinterpret_cast<const uint2*>(
                                bA + (size_t)gidx(selA, e2[r], sl[r]) * strA);
                            if (enB) hB[r] = *reinterpret_cast<const uint2*>(
                                bB + (size_t)gidx(selB, e2[r], sl[r]) * strB);
                        }
                    }
#pragma unroll
                    for (int r = 0; r < 4; ++r) {
                        if (j < cc[r]) {
                            ac[r][0] += bf2f(hA[r].x & 0xffffu); ac[r][1] += bf2f(hA[r].x >> 16);
                            ac[r][2] += bf2f(hA[r].y & 0xffffu); ac[r][3] += bf2f(hA[r].y >> 16);
                            ac[r][4] += bf2f(hB[r].x & 0xffffu); ac[r][5] += bf2f(hB[r].x >> 16);
                            ac[r][6] += bf2f(hB[r].y & 0xffffu); ac[r][7] += bf2f(hB[r].y >> 16);
                        }
                    }
                }
#pragma unroll
                for (int r = 0; r < 4; ++r) {
                    float ci = 1.0f / fmaxf((float)cc[r], 1.0f);
                    uint4 o;
                    if (u < 12) {
                        o = mreg[r];
                    } else {
                        o.x = (u == 12) ? mreg[r].x : pk(ac[r][0] * ci, ac[r][1] * ci);
                        o.y = (u == 12) ? mreg[r].y : pk(ac[r][2] * ci, ac[r][3] * ci);
                        o.z = pk(ac[r][4] * ci, ac[r][5] * ci);
                        o.w = pk(ac[r][6] * ci, ac[r][7] * ci);
                    }
                    if (u < 60) {
                        int nl = rb + r;
                        int byte = (nl * 960 + 16 * u) ^ ((nl & 7) << 4);
                        *reinterpret_cast<uint4*>(reinterpret_cast<char*>(lds) + byte) = o;
                    }
                }
            }
        }
    }
    __syncthreads();

    // ---- MFMA phase: fully unrolled K loop ----
    int l15 = lane & 15;
    int kg8 = (lane >> 4) << 3;
    int f0 = (wv == 0) ? 0 : (4 + 3 * (wv - 1));
    int cw = (wv == 0) ? 4 : 3;

    f32x4 acc[4][4];
#pragma unroll
    for (int g = 0; g < 4; ++g)
#pragma unroll
        for (int i = 0; i < 4; ++i) acc[g][i] = (f32x4){0.f, 0.f, 0.f, 0.f};

    const bf16x8* BpB = reinterpret_cast<const bf16x8*>(Bp);
    const char* ldsc = reinterpret_cast<const char*>(lds);

#pragma unroll
    for (int ks = 0; ks < KS; ++ks) {
        int k0 = ks * 32 + kg8;
        const bf16x8* bp = BpB + ((size_t)(ks * NFRAG + f0)) * 64 + lane;
        bf16x8 b[4];
#pragma unroll
        for (int i = 0; i < 4; ++i)
            if (i < cw) b[i] = bp[i * 64];
#pragma unroll
        for (int g = 0; g < 4; ++g) {
            int r = g * 16 + l15;
            int ab = (r * 960 + 2 * k0) ^ ((r & 7) << 4);
            bf16x8 a = *reinterpret_cast<const bf16x8*>(ldsc + ab);
#pragma unroll
            for (int i = 0; i < 4; ++i)
                if (i < cw)
                    acc[g][i] = __builtin_amdgcn_mfma_f32_16x16x32_bf16(a, b[i], acc[g][i], 0, 0, 0);
        }
    }

    // ---- epilogue mv prefetch (bf16 membf row of the slot's node) ----
    float mv[13];
    {
        const char* membc = reinterpret_cast<const char*>(membf);
#pragma unroll
        for (int t = 0; t < 13; ++t) {
            int idx = tid + t * 512;
            mv[t] = 0.f;
            if (idx < NB * MD) {
                int n = idx / MD, j = idx - n * MD;
                int nd = node_s[n];
                if (nd >= 0) {
                    unsigned short h = *reinterpret_cast<const unsigned short*>(
                        membc + (size_t)nd * 208 + 2 * j);
                    mv[t] = bf2f((unsigned int)h);
                }
            }
        }
    }

    __syncthreads();  // reuse LDS as Gl[400][GLS] bf16

    unsigned short* Gl = lds;
    int kq = (lane >> 4) << 2;
#pragma unroll
    for (int i = 0; i < 4; ++i) {
        if (i < cw) {
            int col = (f0 + i) * 16 + l15;
            float bias = (col < 200) ? (b_ih[col] + b_hh[col])
                       : (col < 300) ? b_ih[col] : b_hh[col - 100];
#pragma unroll
            for (int g = 0; g < 4; ++g) {
                int node = g * 16 + kq;
#pragma unroll
                for (int rp = 0; rp < 2; ++rp) {
                    *reinterpret_cast<unsigned int*>(&Gl[col * GLS + node + 2 * rp]) =
                        pk(acc[g][i][2 * rp] + bias, acc[g][i][2 * rp + 1] + bias);
                }
            }
        }
    }
    __syncthreads();

#pragma unroll
    for (int t = 0; t < 13; ++t) {
        int idx = tid + t * 512;
        if (idx < NB * MD) {
            int n = idx / MD, j = idx - n * MD;
            int nd = node_s[n];
            if (nd >= 0) {
                float rp = bf2f((unsigned int)Gl[j * GLS + n]);
                float zp = bf2f((unsigned int)Gl[(100 + j) * GLS + n]);
                float inp = bf2f((unsigned int)Gl[(200 + j) * GLS + n]);
                float hnp = bf2f((unsigned int)Gl[(300 + j) * GLS + n]);
                float r = fast_sigmoid(rp);
                float z = fast_sigmoid(zp);
                float nn = fast_tanh(fmaf(r, hnp, inp));
                float h = (1.0f - z) * nn + z * mv[t];
                out[(size_t)nd * MD + j] = h;
            }
        }
    }
}

extern "C" void kernel_launch(void* const* d_in, const int* in_sizes, int n_in,
                              void* d_out, int out_size, void* d_ws, size_t ws_size,
                              hipStream_t stream)
{
    const float* memory      = (const float*)d_in[0];
    const float* raw_msg     = (const float*)d_in[1];
    const float* time_w      = (const float*)d_in[2];
    const float* time_b      = (const float*)d_in[3];
    const float* w_ih        = (const float*)d_in[4];
    const float* w_hh        = (const float*)d_in[5];
    const float* b_ih        = (const float*)d_in[6];
    const float* b_hh        = (const float*)d_in[7];
    const int*   last_update = (const int*)d_in[8];
    const int*   src         = (const int*)d_in[9];
    const int*   dst         = (const int*)d_in[10];
    const int*   tarr        = (const int*)d_in[11];
    float* out = (float*)d_out;

    // ws: cnt[N] off[N] cur[N] tpos[N] psum[256] psumC[1024] clsBase[4] ntp[4]
    //     | entries int4[2E] | tinfo int4[N] | tencbf u32[2E*50]
    //     | membf uint4[N*13] | rawbf uint4[E*22] | Bp
    int* cnt     = (int*)d_ws;
    int* off     = cnt + NND;
    int* cur     = off + NND;
    int* tpos    = cur + NND;
    int* psum    = tpos + NND;
    int* psumC   = psum + 256;
    int* clsBase = psumC + 1024;
    int* ntp     = clsBase + 4;
    int4* entries = (int4*)(ntp + 4);
    int4* tinfo = entries + 2 * NEV;
    unsigned int* tencbf = (unsigned int*)(tinfo + NND);
    uint4* membf = (uint4*)(tencbf + (size_t)2 * NEV * 50);
    uint4* rawbf = membf + (size_t)NND * 13;
    unsigned short* Bp = (unsigned short*)(rawbf + (size_t)NEV * 22);
    size_t need = (size_t)((char*)(Bp + BP_ELEMS) - (char*)d_ws);
    if (ws_size < need) return;

    const int NBLK = (NND + 1023) / 1024;  // 196
    const int NTILE = NND / NB;            // 3125
    const int CVT_TOTAL = BP_ELEMS + NEV * 22 + NEV;
    const int PC_TOTAL = NND * 13 + NEV;

    hipMemsetAsync(cnt, 0, NND * sizeof(int), stream);
    k_convert<<<(CVT_TOTAL + 255) / 256, 256, 0, stream>>>(w_ih, w_hh, raw_msg,
                                                           src, dst, Bp, rawbf, cnt);
    k_scan1<<<NBLK, 256, 0, stream>>>(cnt, off, tpos, psum, psumC);
    k_scan2<<<1, 256, 0, stream>>>(psum, psumC, clsBase, ntp, NBLK);
    k_scan3<<<NBLK, 256, 0, stream>>>(cnt, off, tpos, psum, psumC, clsBase, cur);
    k_placecopy<<<(PC_TOTAL + 255) / 256, 256, 0, stream>>>(memory, cnt, off, tpos,
                                                            src, dst, tarr, last_update,
                                                            cur, out, membf, tinfo, entries);
    k_tenc<<<NEV, 256, 0, stream>>>(entries, time_w, time_b, tencbf);
    tgn_gemm<<<NTILE, 512, 0, stream>>>(membf, rawbf, tencbf, entries,
                                        Bp, b_ih, b_hh, ntp, tinfo, out);
}